// Round 8
// baseline (151.274 us; speedup 1.0000x reference)
//
#include <hip/hip_runtime.h>
#include <math.h>

#define B 4
#define N 512
#define IN_DIM 128
#define OUT_DIM 128
#define HEADS 4
#define PER_HEAD 32
#define NT (N / 64)        // 8 j-tiles of 64
#define IT 4               // target nodes per attn block (sweet spot)
#define WV 4               // waves per attn block; wave w owns jt {w, w+4}
#define NJT (NT / WV)      // 2 j-tiles per wave
#define NCH 4              // phase-1 channel chunks of 8
#define LROWS 4            // rows per block (linear) -- R10-proven
#define LIN_BLOCKS (B * N / LROWS)   // 512
#define MASK_BLOCKS 512

// R17. R16 post-mortem: spill fix landed exactly as predicted (WRITE 45->1MB,
// FETCH 32->9.5MB) but attn only 50->41.6us. Counters: VALUBusy 35.8%,
// Occupancy 33.6%, HBM 3%, conflicts 0 => LATENCY-bound, not traffic-bound.
// Ladder re-read: best attn was IT=4 (R10, ~14us) at only 2 waves/SIMD;
// L2 traffic stops mattering past IT~4 (L2 absorbs; FETCH tiny). So the
// lever is occupancy x short chains: IT=4, 4-wave blocks, wave w owns
// j-tiles {w,w+4}. Grid (128,4,4)=2048 blocks x 4 waves = 8192 waves =
// 32 waves/CU (8/SIMD, FULL). LDS 10.4KB -> 8 blocks/CU fits.
// launch_bounds(256,8) caps VGPR at 64 (peak live ~50, no spill).
// Cross-wave softmax machinery identical to the R12/R16-verified pattern.

typedef float v2f __attribute__((ext_vector_type(2)));

static __device__ inline v2f mk2(float a, float b) {
    v2f r; r.x = a; r.y = b; return r;
}

// ---------------------------------------------------------------------------
// Kernel 1 (fat): blocks [0,512): xl = x@Wl+bl ; xr = x@Wr+br, xlT in
// channel-group-of-4 layout, plus axl/axr att-dots (half-wave reduce).
// Blocks [512,1024): adjacency bitmask, transposed, diagonal forced.
// (R10-proven, verbatim.)
// ---------------------------------------------------------------------------
__global__ __launch_bounds__(128) void gat_prep(
    const float* __restrict__ x, const float* __restrict__ Wl,
    const float* __restrict__ bl, const float* __restrict__ Wr,
    const float* __restrict__ br, const float* __restrict__ att,
    const int* __restrict__ adj,
    float* __restrict__ xl, float* __restrict__ xr, float* __restrict__ xlT,
    float* __restrict__ axl, float* __restrict__ axr,
    unsigned long long* __restrict__ maskT) {
    const int bid = blockIdx.x;
    __shared__ float xs[LROWS][IN_DIM];

    if (bid < LIN_BLOCKS) {
        // ---- linear role ----
        const int r0  = bid * LROWS;
        const int col = threadIdx.x;          // col = h*32 + c
#pragma unroll
        for (int r = 0; r < LROWS; ++r)
            xs[r][col] = x[(r0 + r) * IN_DIM + col];
        __syncthreads();

        float accl[LROWS], accr[LROWS];
        {
            const float blv = bl[col];
            const float brv = br[col];
#pragma unroll
            for (int r = 0; r < LROWS; ++r) { accl[r] = blv; accr[r] = brv; }
        }
#pragma unroll 8
        for (int k = 0; k < IN_DIM; ++k) {
            const float wl = Wl[k * OUT_DIM + col];
            const float wr = Wr[k * OUT_DIM + col];
#pragma unroll
            for (int r = 0; r < LROWS; ++r) {
                accl[r] = fmaf(xs[r][k], wl, accl[r]);
                accr[r] = fmaf(xs[r][k], wr, accr[r]);
            }
        }
        const float attc = att[col];
        const int h = col >> 5;
#pragma unroll
        for (int r = 0; r < LROWS; ++r) {
            const int row = r0 + r;
            const int b = row >> 9, n = row & (N - 1);
            xl[row * OUT_DIM + col] = accl[r];
            xr[row * OUT_DIM + col] = accr[r];
            xlT[((b * 32 + (col >> 2)) * N + n) * 4 + (col & 3)] = accl[r];
            float pl = attc * accl[r];
            float pr = attc * accr[r];
#pragma unroll
            for (int d = 1; d < 32; d <<= 1) {
                pl += __shfl_xor(pl, d);
                pr += __shfl_xor(pr, d);
            }
            if ((col & 31) == 0) {
                axl[(b * HEADS + h) * N + n] = pl;
                axr[(b * HEADS + h) * N + n] = pr;
            }
        }
    } else {
        // ---- mask role: 512 sub-blocks, 16 adj loads per lane ----
        const int mid  = bid - LIN_BLOCKS;    // 0..511
        const int mb   = mid >> 7;            // batch
        const int it6  = (mid >> 4) & 7;      // i-tile of 64
        const int th   = mid & 15;
        const int t    = th >> 1;             // j-tile of 64
        const int half = th & 1;              // which u32 of the u64
        const int w    = threadIdx.x >> 6;    // wave: low/high u16 of the u32
        const int i    = it6 * 64 + (threadIdx.x & 63);
        const int j0   = t * 64 + half * 32 + w * 16;
        unsigned int bits = 0;
#pragma unroll
        for (int k = 0; k < 16; ++k) {
            const int j = j0 + k;
            bits |= (unsigned int)(adj[((size_t)mb * N + j) * N + i] != 0) << k;
        }
        const int p = (i & 63) - (half * 32 + w * 16);
        if ((i >> 6) == t && (unsigned)p < 16u) bits |= 1u << p;
        unsigned short* m16 = (unsigned short*)maskT;
        m16[(((size_t)mb * N + i) * NT + t) * 4 + half * 2 + w] =
            (unsigned short)bits;
    }
}

// ---------------------------------------------------------------------------
// Kernel 2: fused scores + segment-softmax + aggregation.
// 4 waves/block; wave w owns j-tiles {w, w+4}. IT=4 targets.
// Full occupancy: 2048 blocks x 256 thr = 32 waves/CU; VGPR capped 64.
// ---------------------------------------------------------------------------
__global__ __launch_bounds__(256, 8) void gat_attn(
    const float* __restrict__ xl, const float* __restrict__ xr,
    const float* __restrict__ xlT, const float* __restrict__ axl,
    const float* __restrict__ axr,
    const unsigned long long* __restrict__ maskT,
    const float* __restrict__ att, const float* __restrict__ bias,
    float* __restrict__ out) {
    const int tid  = threadIdx.x;
    const int lane = tid & 63;
    const int wv   = tid >> 6;            // wave id
    const int h    = blockIdx.y;
    const int i0   = blockIdx.x * IT;
    const int b    = blockIdx.z;

    __shared__ __align__(16) float a_s[IT][N];              // 8 KB (wave-private slices)
    __shared__ __align__(16) float part[WV][IT][PER_HEAD];  // 2 KB
    __shared__ __align__(16) float red[2][IT][WV];          // 128 B (max, sum)

    // ---- Phase 1: att-dot |x_i + x_j| term over own 2 j-tiles ----
    float e[IT][NJT];
#pragma unroll
    for (int ii = 0; ii < IT; ++ii)
#pragma unroll
        for (int jtl = 0; jtl < NJT; ++jtl) e[ii][jtl] = 0.f;

    const float4* xlT4 = (const float4*)xlT + (size_t)(b * 32 + h * 8) * N;

#pragma unroll 1
    for (int ch = 0; ch < NCH; ++ch) {
        v2f att2[4];
#pragma unroll
        for (int cc = 0; cc < 4; ++cc) {
            const int c = h * PER_HEAD + ch * 8 + cc * 2;
            att2[cc] = mk2(0.4f * att[c], 0.4f * att[c + 1]);
        }
#pragma unroll
        for (int jtl = 0; jtl < NJT; ++jtl) {
            const int jt = wv + jtl * WV;
            const int j  = jt * 64 + lane;
            v2f xlv[4];
#pragma unroll
            for (int q = 0; q < 2; ++q) {
                const float4 v = xlT4[(ch * 2 + q) * N + j];
                xlv[q * 2 + 0] = mk2(v.x, v.y);
                xlv[q * 2 + 1] = mk2(v.z, v.w);
            }
#pragma unroll
            for (int ii = 0; ii < IT; ++ii) {
                const float4* xrp = (const float4*)(
                    xr + (size_t)(b * N + i0 + ii) * OUT_DIM + h * PER_HEAD + ch * 8);
                const float4 v0 = xrp[0];
                const float4 v1 = xrp[1];
                v2f xr2[4];
                xr2[0] = mk2(v0.x, v0.y);
                xr2[1] = mk2(v0.z, v0.w);
                xr2[2] = mk2(v1.x, v1.y);
                xr2[3] = mk2(v1.z, v1.w);
                v2f acc = mk2(0.f, 0.f);
#pragma unroll
                for (int cc = 0; cc < 4; ++cc) {
                    v2f s = xr2[cc] + xlv[cc];            // v_pk_add_f32
                    s = __builtin_elementwise_max(s, -s); // v_pk_max_f32 (neg mod)
                    acc = __builtin_elementwise_fma(att2[cc], s, acc); // v_pk_fma
                }
                e[ii][jtl] += acc.x + acc.y;
            }
        }
    }

    // ---- finalize scores: 0.6*(axr_i + axl_j) + mask ----
    float axr_i[IT];
#pragma unroll
    for (int ii = 0; ii < IT; ++ii)
        axr_i[ii] = axr[(b * HEADS + h) * N + i0 + ii];
    const float* axlh = axl + (size_t)(b * HEADS + h) * N;
#pragma unroll
    for (int jtl = 0; jtl < NJT; ++jtl) {
        const int jt = wv + jtl * WV;
        const int j  = jt * 64 + lane;
        const float alj = axlh[j];
#pragma unroll
        for (int ii = 0; ii < IT; ++ii) {
            const unsigned long long m =
                maskT[(size_t)(b * N + i0 + ii) * NT + jt];
            const float ev = fmaf(0.6f, axr_i[ii] + alj, e[ii][jtl]);
            e[ii][jtl] = ((m >> lane) & 1ull) ? ev : -1e30f;
        }
    }

    // ---- Phase 2a: per-wave max -> LDS ----
#pragma unroll
    for (int ii = 0; ii < IT; ++ii) {
        float m = fmaxf(e[ii][0], e[ii][1]);
#pragma unroll
        for (int d = 1; d < 64; d <<= 1) m = fmaxf(m, __shfl_xor(m, d));
        if (lane == 0) red[0][ii][wv] = m;
    }
    __syncthreads();

    // ---- Phase 2b: global max, exp, per-wave sum -> LDS ----
#pragma unroll
    for (int ii = 0; ii < IT; ++ii) {
        const float4 r0 = *(const float4*)&red[0][ii][0];
        const float m = fmaxf(fmaxf(r0.x, r0.y), fmaxf(r0.z, r0.w));
        float ps = 0.f;
#pragma unroll
        for (int jtl = 0; jtl < NJT; ++jtl) {
            const int jt = wv + jtl * WV;
            const int j  = jt * 64 + lane;
            const float a = __expf(e[ii][jtl] - m);
            a_s[ii][j] = a;
            ps += a;
        }
#pragma unroll
        for (int d = 1; d < 64; d <<= 1) ps += __shfl_xor(ps, d);
        if (lane == 0) red[1][ii][wv] = ps;
    }
    // no barrier: a_s slices are wave-private; red[1] is read only after the
    // phase-3 barrier below.

    // ---- Phase 3: aggregation over own 2 j-tiles; LDS partial reduce ----
    const int c4 = (lane & 7) * 4;
    const int jg = lane >> 3;
    const float* xlb = xl + (size_t)(b * N) * OUT_DIM + h * PER_HEAD + c4;

    v2f accA[IT], accB[IT];
#pragma unroll
    for (int ii = 0; ii < IT; ++ii) {
        accA[ii] = mk2(0.f, 0.f);
        accB[ii] = mk2(0.f, 0.f);
    }
#pragma unroll
    for (int jtl = 0; jtl < NJT; ++jtl) {
        const int jt = wv + jtl * WV;
#pragma unroll
        for (int jo = 0; jo < 8; ++jo) {
            const int jj = jt * 64 + jo * 8 + jg;
            const float4 xv = *(const float4*)(xlb + (size_t)jj * OUT_DIM);
            const v2f x0 = mk2(xv.x, xv.y);
            const v2f x1 = mk2(xv.z, xv.w);
#pragma unroll
            for (int ii = 0; ii < IT; ++ii) {
                const float av = a_s[ii][jj];
                const v2f av2 = mk2(av, av);
                accA[ii] = __builtin_elementwise_fma(av2, x0, accA[ii]);
                accB[ii] = __builtin_elementwise_fma(av2, x1, accB[ii]);
            }
        }
    }
#pragma unroll
    for (int ii = 0; ii < IT; ++ii) {
        float rx = accA[ii].x, ry = accA[ii].y;
        float rz = accB[ii].x, rw = accB[ii].y;
#pragma unroll
        for (int d = 8; d < 64; d <<= 1) {
            rx += __shfl_xor(rx, d);
            ry += __shfl_xor(ry, d);
            rz += __shfl_xor(rz, d);
            rw += __shfl_xor(rw, d);
        }
        if (jg == 0)
            *(float4*)&part[wv][ii][c4] = make_float4(rx, ry, rz, rw);
    }
    __syncthreads();

    // ---- finalize: threads 0..127 -> (ii = tid>>5, c = tid&31) ----
    if (tid < IT * PER_HEAD) {
        const int ii = tid >> 5;
        const int c  = tid & 31;
        float v = 0.f;
#pragma unroll
        for (int w = 0; w < WV; ++w) v += part[w][ii][c];
        float ssum = 0.f;
#pragma unroll
        for (int w = 0; w < WV; ++w) ssum += red[1][ii][w];
        const float s = 1.f / ssum;
        out[(size_t)(b * N + i0 + ii) * OUT_DIM + h * PER_HEAD + c] =
            v * s + bias[h * PER_HEAD + c];
    }
}

extern "C" void kernel_launch(void* const* d_in, const int* in_sizes, int n_in,
                              void* d_out, int out_size, void* d_ws, size_t ws_size,
                              hipStream_t stream) {
    const float* x    = (const float*)d_in[0];
    const int*   adj  = (const int*)d_in[1];
    const float* Wl   = (const float*)d_in[2];
    const float* bl   = (const float*)d_in[3];
    const float* Wr   = (const float*)d_in[4];
    const float* br   = (const float*)d_in[5];
    const float* att  = (const float*)d_in[6];
    const float* bias = (const float*)d_in[7];
    float* out = (float*)d_out;

    char* ws = (char*)d_ws;
    float* xl   = (float*)(ws);                         // 1 MB
    float* xr   = (float*)(ws + (1u << 20));            // 1 MB
    float* xlT  = (float*)(ws + (2u << 20));            // 1 MB
    unsigned long long* maskT =
        (unsigned long long*)(ws + (3u << 20));         // 128 KB
    float* axl  = (float*)(ws + (3u << 20) + (1u << 17));              // 32 KB
    float* axr  = (float*)(ws + (3u << 20) + (1u << 17) + (1u << 15)); // 32 KB

    gat_prep<<<dim3(LIN_BLOCKS + MASK_BLOCKS), dim3(128), 0, stream>>>(
        x, Wl, bl, Wr, br, att, adj, xl, xr, xlT, axl, axr, maskT);
    gat_attn<<<dim3(N / IT, HEADS, B), dim3(256), 0, stream>>>(
        xl, xr, xlT, axl, axr, maskT, att, bias, out);
}

// Round 9
// 148.090 us; speedup vs baseline: 1.0215x; 1.0215x over previous
//
#include <hip/hip_runtime.h>
#include <math.h>

#define B 4
#define N 512
#define IN_DIM 128
#define OUT_DIM 128
#define HEADS 4
#define PER_HEAD 32
#define NT (N / 64)        // 8 j-tiles of 64
#define IT 4               // target nodes per attn block (proven sweet spot)
#define WV 2               // waves per attn block; wave w owns jt {w, w+2, ...}
#define NJT (NT / WV)      // 4 j-tiles per wave
#define NCH 4              // phase-1 channel chunks of 8
#define LROWS 4            // rows per block (linear) -- R10-proven
#define LIN_BLOCKS (B * N / LROWS)   // 512
#define MASK_BLOCKS 512

// R18. R17 post-mortem: __launch_bounds__(256,8) forced a 32-VGPR budget for
// a ~55-reg live set -> catastrophic spill (FETCH 133MB + WRITE 144MB = 280MB
// scratch traffic = the whole 84us). Occupancy hit 70% and was worthless.
// Structure was never fairly tested. Ladder: R10 (IT=4, 1-wave blocks, 8
// waves/CU, no barriers) remains best attn (~10-14us); kernel is LATENCY-
// bound -> need more waves at IT=4 with short chains and NO forced reg cap.
// R18: 2-wave blocks (128thr), wave w owns j-tiles {w,w+2,w+4,w+6}; grid
// 2048 x 2 waves = 4096 waves = 16 waves/CU (2x R10). launch_bounds(128,4)
// = 128-VGPR cap; expected alloc ~56-64, no spill; 2 barriers/block;
// softmax exchange = 2 scalars per target via tiny LDS.

typedef float v2f __attribute__((ext_vector_type(2)));

static __device__ inline v2f mk2(float a, float b) {
    v2f r; r.x = a; r.y = b; return r;
}

// ---------------------------------------------------------------------------
// Kernel 1 (fat): blocks [0,512): xl = x@Wl+bl ; xr = x@Wr+br, xlT in
// channel-group-of-4 layout, plus axl/axr att-dots (half-wave reduce).
// Blocks [512,1024): adjacency bitmask, transposed, diagonal forced.
// (R10-proven, verbatim.)
// ---------------------------------------------------------------------------
__global__ __launch_bounds__(128) void gat_prep(
    const float* __restrict__ x, const float* __restrict__ Wl,
    const float* __restrict__ bl, const float* __restrict__ Wr,
    const float* __restrict__ br, const float* __restrict__ att,
    const int* __restrict__ adj,
    float* __restrict__ xl, float* __restrict__ xr, float* __restrict__ xlT,
    float* __restrict__ axl, float* __restrict__ axr,
    unsigned long long* __restrict__ maskT) {
    const int bid = blockIdx.x;
    __shared__ float xs[LROWS][IN_DIM];

    if (bid < LIN_BLOCKS) {
        // ---- linear role ----
        const int r0  = bid * LROWS;
        const int col = threadIdx.x;          // col = h*32 + c
#pragma unroll
        for (int r = 0; r < LROWS; ++r)
            xs[r][col] = x[(r0 + r) * IN_DIM + col];
        __syncthreads();

        float accl[LROWS], accr[LROWS];
        {
            const float blv = bl[col];
            const float brv = br[col];
#pragma unroll
            for (int r = 0; r < LROWS; ++r) { accl[r] = blv; accr[r] = brv; }
        }
#pragma unroll 8
        for (int k = 0; k < IN_DIM; ++k) {
            const float wl = Wl[k * OUT_DIM + col];
            const float wr = Wr[k * OUT_DIM + col];
#pragma unroll
            for (int r = 0; r < LROWS; ++r) {
                accl[r] = fmaf(xs[r][k], wl, accl[r]);
                accr[r] = fmaf(xs[r][k], wr, accr[r]);
            }
        }
        const float attc = att[col];
        const int h = col >> 5;
#pragma unroll
        for (int r = 0; r < LROWS; ++r) {
            const int row = r0 + r;
            const int b = row >> 9, n = row & (N - 1);
            xl[row * OUT_DIM + col] = accl[r];
            xr[row * OUT_DIM + col] = accr[r];
            xlT[((b * 32 + (col >> 2)) * N + n) * 4 + (col & 3)] = accl[r];
            float pl = attc * accl[r];
            float pr = attc * accr[r];
#pragma unroll
            for (int d = 1; d < 32; d <<= 1) {
                pl += __shfl_xor(pl, d);
                pr += __shfl_xor(pr, d);
            }
            if ((col & 31) == 0) {
                axl[(b * HEADS + h) * N + n] = pl;
                axr[(b * HEADS + h) * N + n] = pr;
            }
        }
    } else {
        // ---- mask role: 512 sub-blocks, 16 adj loads per lane ----
        const int mid  = bid - LIN_BLOCKS;    // 0..511
        const int mb   = mid >> 7;            // batch
        const int it6  = (mid >> 4) & 7;      // i-tile of 64
        const int th   = mid & 15;
        const int t    = th >> 1;             // j-tile of 64
        const int half = th & 1;              // which u32 of the u64
        const int w    = threadIdx.x >> 6;    // wave: low/high u16 of the u32
        const int i    = it6 * 64 + (threadIdx.x & 63);
        const int j0   = t * 64 + half * 32 + w * 16;
        unsigned int bits = 0;
#pragma unroll
        for (int k = 0; k < 16; ++k) {
            const int j = j0 + k;
            bits |= (unsigned int)(adj[((size_t)mb * N + j) * N + i] != 0) << k;
        }
        const int p = (i & 63) - (half * 32 + w * 16);
        if ((i >> 6) == t && (unsigned)p < 16u) bits |= 1u << p;
        unsigned short* m16 = (unsigned short*)maskT;
        m16[(((size_t)mb * N + i) * NT + t) * 4 + half * 2 + w] =
            (unsigned short)bits;
    }
}

// ---------------------------------------------------------------------------
// Kernel 2: fused scores + segment-softmax + aggregation.
// 2 waves/block; wave w owns j-tiles {w, w+2, w+4, w+6}. IT=4 targets.
// 2048 blocks x 2 waves = 4096 waves = 16 waves/CU. No forced VGPR cap
// beyond 128; expected alloc ~56-64 (8 waves/SIMD if <=64).
// ---------------------------------------------------------------------------
__global__ __launch_bounds__(128, 4) void gat_attn(
    const float* __restrict__ xl, const float* __restrict__ xr,
    const float* __restrict__ xlT, const float* __restrict__ axl,
    const float* __restrict__ axr,
    const unsigned long long* __restrict__ maskT,
    const float* __restrict__ att, const float* __restrict__ bias,
    float* __restrict__ out) {
    const int tid  = threadIdx.x;
    const int lane = tid & 63;
    const int wv   = tid >> 6;            // wave id (0,1)
    const int h    = blockIdx.y;
    const int i0   = blockIdx.x * IT;
    const int b    = blockIdx.z;

    __shared__ __align__(16) float a_s[IT][N];              // 8 KB (wave-private slices)
    __shared__ __align__(16) float part[WV][IT][PER_HEAD];  // 1 KB
    __shared__ __align__(16) float red[2][IT][WV];          // 64 B (max, sum)

    // ---- Phase 1: att-dot |x_i + x_j| term over own 4 j-tiles ----
    float e[IT][NJT];
#pragma unroll
    for (int ii = 0; ii < IT; ++ii)
#pragma unroll
        for (int jtl = 0; jtl < NJT; ++jtl) e[ii][jtl] = 0.f;

    const float4* xlT4 = (const float4*)xlT + (size_t)(b * 32 + h * 8) * N;

#pragma unroll 1
    for (int ch = 0; ch < NCH; ++ch) {
        v2f att2[4];
#pragma unroll
        for (int cc = 0; cc < 4; ++cc) {
            const int c = h * PER_HEAD + ch * 8 + cc * 2;
            att2[cc] = mk2(0.4f * att[c], 0.4f * att[c + 1]);
        }
#pragma unroll
        for (int jtl = 0; jtl < NJT; ++jtl) {
            const int jt = wv + jtl * WV;
            const int j  = jt * 64 + lane;
            v2f xlv[4];
#pragma unroll
            for (int q = 0; q < 2; ++q) {
                const float4 v = xlT4[(ch * 2 + q) * N + j];
                xlv[q * 2 + 0] = mk2(v.x, v.y);
                xlv[q * 2 + 1] = mk2(v.z, v.w);
            }
#pragma unroll
            for (int ii = 0; ii < IT; ++ii) {
                const float4* xrp = (const float4*)(
                    xr + (size_t)(b * N + i0 + ii) * OUT_DIM + h * PER_HEAD + ch * 8);
                const float4 v0 = xrp[0];
                const float4 v1 = xrp[1];
                v2f xr2[4];
                xr2[0] = mk2(v0.x, v0.y);
                xr2[1] = mk2(v0.z, v0.w);
                xr2[2] = mk2(v1.x, v1.y);
                xr2[3] = mk2(v1.z, v1.w);
                v2f acc = mk2(0.f, 0.f);
#pragma unroll
                for (int cc = 0; cc < 4; ++cc) {
                    v2f s = xr2[cc] + xlv[cc];            // v_pk_add_f32
                    s = __builtin_elementwise_max(s, -s); // v_pk_max_f32 (neg mod)
                    acc = __builtin_elementwise_fma(att2[cc], s, acc); // v_pk_fma
                }
                e[ii][jtl] += acc.x + acc.y;
            }
        }
    }

    // ---- finalize scores: 0.6*(axr_i + axl_j) + mask ----
    float axr_i[IT];
#pragma unroll
    for (int ii = 0; ii < IT; ++ii)
        axr_i[ii] = axr[(b * HEADS + h) * N + i0 + ii];
    const float* axlh = axl + (size_t)(b * HEADS + h) * N;
#pragma unroll
    for (int jtl = 0; jtl < NJT; ++jtl) {
        const int jt = wv + jtl * WV;
        const int j  = jt * 64 + lane;
        const float alj = axlh[j];
#pragma unroll
        for (int ii = 0; ii < IT; ++ii) {
            const unsigned long long m =
                maskT[(size_t)(b * N + i0 + ii) * NT + jt];
            const float ev = fmaf(0.6f, axr_i[ii] + alj, e[ii][jtl]);
            e[ii][jtl] = ((m >> lane) & 1ull) ? ev : -1e30f;
        }
    }

    // ---- Phase 2a: per-wave max -> LDS ----
#pragma unroll
    for (int ii = 0; ii < IT; ++ii) {
        float m = fmaxf(fmaxf(e[ii][0], e[ii][1]), fmaxf(e[ii][2], e[ii][3]));
#pragma unroll
        for (int d = 1; d < 64; d <<= 1) m = fmaxf(m, __shfl_xor(m, d));
        if (lane == 0) red[0][ii][wv] = m;
    }
    __syncthreads();

    // ---- Phase 2b: global max, exp, per-wave sum -> LDS ----
#pragma unroll
    for (int ii = 0; ii < IT; ++ii) {
        const float m = fmaxf(red[0][ii][0], red[0][ii][1]);
        float ps = 0.f;
#pragma unroll
        for (int jtl = 0; jtl < NJT; ++jtl) {
            const int jt = wv + jtl * WV;
            const int j  = jt * 64 + lane;
            const float a = __expf(e[ii][jtl] - m);
            a_s[ii][j] = a;
            ps += a;
        }
#pragma unroll
        for (int d = 1; d < 64; d <<= 1) ps += __shfl_xor(ps, d);
        if (lane == 0) red[1][ii][wv] = ps;
    }
    // no barrier: a_s slices are wave-private; red[1] is read only after the
    // phase-3 barrier below.

    // ---- Phase 3: aggregation over own 4 j-tiles; LDS partial reduce ----
    const int c4 = (lane & 7) * 4;
    const int jg = lane >> 3;
    const float* xlb = xl + (size_t)(b * N) * OUT_DIM + h * PER_HEAD + c4;

    v2f accA[IT], accB[IT];
#pragma unroll
    for (int ii = 0; ii < IT; ++ii) {
        accA[ii] = mk2(0.f, 0.f);
        accB[ii] = mk2(0.f, 0.f);
    }
#pragma unroll
    for (int jtl = 0; jtl < NJT; ++jtl) {
        const int jt = wv + jtl * WV;
#pragma unroll
        for (int jo = 0; jo < 8; ++jo) {
            const int jj = jt * 64 + jo * 8 + jg;
            const float4 xv = *(const float4*)(xlb + (size_t)jj * OUT_DIM);
            const v2f x0 = mk2(xv.x, xv.y);
            const v2f x1 = mk2(xv.z, xv.w);
#pragma unroll
            for (int ii = 0; ii < IT; ++ii) {
                const float av = a_s[ii][jj];
                const v2f av2 = mk2(av, av);
                accA[ii] = __builtin_elementwise_fma(av2, x0, accA[ii]);
                accB[ii] = __builtin_elementwise_fma(av2, x1, accB[ii]);
            }
        }
    }
#pragma unroll
    for (int ii = 0; ii < IT; ++ii) {
        float rx = accA[ii].x, ry = accA[ii].y;
        float rz = accB[ii].x, rw = accB[ii].y;
#pragma unroll
        for (int d = 8; d < 64; d <<= 1) {
            rx += __shfl_xor(rx, d);
            ry += __shfl_xor(ry, d);
            rz += __shfl_xor(rz, d);
            rw += __shfl_xor(rw, d);
        }
        if (jg == 0)
            *(float4*)&part[wv][ii][c4] = make_float4(rx, ry, rz, rw);
    }
    __syncthreads();

    // ---- finalize: all 128 threads -> (ii = tid>>5, c = tid&31) ----
    {
        const int ii = tid >> 5;
        const int c  = tid & 31;
        float v = 0.f;
#pragma unroll
        for (int w = 0; w < WV; ++w) v += part[w][ii][c];
        const float ssum = red[1][ii][0] + red[1][ii][1];
        const float s = 1.f / ssum;
        out[(size_t)(b * N + i0 + ii) * OUT_DIM + h * PER_HEAD + c] =
            v * s + bias[h * PER_HEAD + c];
    }
}

extern "C" void kernel_launch(void* const* d_in, const int* in_sizes, int n_in,
                              void* d_out, int out_size, void* d_ws, size_t ws_size,
                              hipStream_t stream) {
    const float* x    = (const float*)d_in[0];
    const int*   adj  = (const int*)d_in[1];
    const float* Wl   = (const float*)d_in[2];
    const float* bl   = (const float*)d_in[3];
    const float* Wr   = (const float*)d_in[4];
    const float* br   = (const float*)d_in[5];
    const float* att  = (const float*)d_in[6];
    const float* bias = (const float*)d_in[7];
    float* out = (float*)d_out;

    char* ws = (char*)d_ws;
    float* xl   = (float*)(ws);                         // 1 MB
    float* xr   = (float*)(ws + (1u << 20));            // 1 MB
    float* xlT  = (float*)(ws + (2u << 20));            // 1 MB
    unsigned long long* maskT =
        (unsigned long long*)(ws + (3u << 20));         // 128 KB
    float* axl  = (float*)(ws + (3u << 20) + (1u << 17));              // 32 KB
    float* axr  = (float*)(ws + (3u << 20) + (1u << 17) + (1u << 15)); // 32 KB

    gat_prep<<<dim3(LIN_BLOCKS + MASK_BLOCKS), dim3(128), 0, stream>>>(
        x, Wl, bl, Wr, br, att, adj, xl, xr, xlT, axl, axr, maskT);
    gat_attn<<<dim3(N / IT, HEADS, B), dim3(128), 0, stream>>>(
        xl, xr, xlT, axl, axr, maskT, att, bias, out);
}

// Round 10
// 111.295 us; speedup vs baseline: 1.3592x; 1.3306x over previous
//
#include <hip/hip_runtime.h>
#include <math.h>

#define B 4
#define N 512
#define IN_DIM 128
#define OUT_DIM 128
#define HEADS 4
#define PER_HEAD 32
#define NT (N / 64)        // 8 j-tiles of 64
#define IT 4               // target nodes per attn block
#define WV 2               // waves per attn block; wave w owns jt {w, w+2, ...}
#define NJT (NT / WV)      // 4 j-tiles per wave
#define NCH 8              // phase-1 channel chunks of 4 (live-set < 64 VGPR)
#define LROWS 4            // rows per block (linear) -- R10-proven
#define LIN_BLOCKS (B * N / LROWS)   // 512
#define MASK_BLOCKS 512

// R19. R18 post-mortem: VGPR_Count=64 + FETCH 120MB/WRITE 132MB = spill
// AGAIN. Pattern across R13/R17/R18: hipcc allocates one occupancy bucket
// BELOW the launch_bounds cap (cap128->64, cap64->32) and spills the e[][]
// array. Fix both sides: (1) __launch_bounds__(128) with NO min-waves arg
// -- no allocator pressure, no spill; grid 2048x2-wave = 16 waves/CU needs
// only VGPR<=128, satisfied naturally. (2) live set shrunk below 64:
// phase 1 in NCH=8 chunks of 4 channels (att2[2] + 1 xlT float4/jtl, xr
// float4s hoisted per chunk) -> peak live ~55. Same total load bytes.
// Structure otherwise = R18 (2-wave blocks, IT=4, 2 barriers); prep = R10.

typedef float v2f __attribute__((ext_vector_type(2)));

static __device__ inline v2f mk2(float a, float b) {
    v2f r; r.x = a; r.y = b; return r;
}

// ---------------------------------------------------------------------------
// Kernel 1 (fat): blocks [0,512): xl = x@Wl+bl ; xr = x@Wr+br, xlT in
// channel-group-of-4 layout, plus axl/axr att-dots (half-wave reduce).
// Blocks [512,1024): adjacency bitmask, transposed, diagonal forced.
// (R10-proven, verbatim.)
// ---------------------------------------------------------------------------
__global__ __launch_bounds__(128) void gat_prep(
    const float* __restrict__ x, const float* __restrict__ Wl,
    const float* __restrict__ bl, const float* __restrict__ Wr,
    const float* __restrict__ br, const float* __restrict__ att,
    const int* __restrict__ adj,
    float* __restrict__ xl, float* __restrict__ xr, float* __restrict__ xlT,
    float* __restrict__ axl, float* __restrict__ axr,
    unsigned long long* __restrict__ maskT) {
    const int bid = blockIdx.x;
    __shared__ float xs[LROWS][IN_DIM];

    if (bid < LIN_BLOCKS) {
        // ---- linear role ----
        const int r0  = bid * LROWS;
        const int col = threadIdx.x;          // col = h*32 + c
#pragma unroll
        for (int r = 0; r < LROWS; ++r)
            xs[r][col] = x[(r0 + r) * IN_DIM + col];
        __syncthreads();

        float accl[LROWS], accr[LROWS];
        {
            const float blv = bl[col];
            const float brv = br[col];
#pragma unroll
            for (int r = 0; r < LROWS; ++r) { accl[r] = blv; accr[r] = brv; }
        }
#pragma unroll 8
        for (int k = 0; k < IN_DIM; ++k) {
            const float wl = Wl[k * OUT_DIM + col];
            const float wr = Wr[k * OUT_DIM + col];
#pragma unroll
            for (int r = 0; r < LROWS; ++r) {
                accl[r] = fmaf(xs[r][k], wl, accl[r]);
                accr[r] = fmaf(xs[r][k], wr, accr[r]);
            }
        }
        const float attc = att[col];
        const int h = col >> 5;
#pragma unroll
        for (int r = 0; r < LROWS; ++r) {
            const int row = r0 + r;
            const int b = row >> 9, n = row & (N - 1);
            xl[row * OUT_DIM + col] = accl[r];
            xr[row * OUT_DIM + col] = accr[r];
            xlT[((b * 32 + (col >> 2)) * N + n) * 4 + (col & 3)] = accl[r];
            float pl = attc * accl[r];
            float pr = attc * accr[r];
#pragma unroll
            for (int d = 1; d < 32; d <<= 1) {
                pl += __shfl_xor(pl, d);
                pr += __shfl_xor(pr, d);
            }
            if ((col & 31) == 0) {
                axl[(b * HEADS + h) * N + n] = pl;
                axr[(b * HEADS + h) * N + n] = pr;
            }
        }
    } else {
        // ---- mask role: 512 sub-blocks, 16 adj loads per lane ----
        const int mid  = bid - LIN_BLOCKS;    // 0..511
        const int mb   = mid >> 7;            // batch
        const int it6  = (mid >> 4) & 7;      // i-tile of 64
        const int th   = mid & 15;
        const int t    = th >> 1;             // j-tile of 64
        const int half = th & 1;              // which u32 of the u64
        const int w    = threadIdx.x >> 6;    // wave: low/high u16 of the u32
        const int i    = it6 * 64 + (threadIdx.x & 63);
        const int j0   = t * 64 + half * 32 + w * 16;
        unsigned int bits = 0;
#pragma unroll
        for (int k = 0; k < 16; ++k) {
            const int j = j0 + k;
            bits |= (unsigned int)(adj[((size_t)mb * N + j) * N + i] != 0) << k;
        }
        const int p = (i & 63) - (half * 32 + w * 16);
        if ((i >> 6) == t && (unsigned)p < 16u) bits |= 1u << p;
        unsigned short* m16 = (unsigned short*)maskT;
        m16[(((size_t)mb * N + i) * NT + t) * 4 + half * 2 + w] =
            (unsigned short)bits;
    }
}

// ---------------------------------------------------------------------------
// Kernel 2: fused scores + segment-softmax + aggregation.
// 2 waves/block; wave w owns j-tiles {w, w+2, w+4, w+6}. IT=4 targets.
// 2048 blocks x 2 waves = 16 waves/CU. NO min-waves pressure (anti-spill).
// ---------------------------------------------------------------------------
__global__ __launch_bounds__(128) void gat_attn(
    const float* __restrict__ xl, const float* __restrict__ xr,
    const float* __restrict__ xlT, const float* __restrict__ axl,
    const float* __restrict__ axr,
    const unsigned long long* __restrict__ maskT,
    const float* __restrict__ att, const float* __restrict__ bias,
    float* __restrict__ out) {
    const int tid  = threadIdx.x;
    const int lane = tid & 63;
    const int wv   = tid >> 6;            // wave id (0,1)
    const int h    = blockIdx.y;
    const int i0   = blockIdx.x * IT;
    const int b    = blockIdx.z;

    __shared__ __align__(16) float a_s[IT][N];              // 8 KB (wave-private slices)
    __shared__ __align__(16) float part[WV][IT][PER_HEAD];  // 1 KB
    __shared__ __align__(16) float red[2][IT][WV];          // 64 B (max, sum)

    // ---- Phase 1: att-dot |x_i + x_j| term over own 4 j-tiles ----
    float e[IT][NJT];
#pragma unroll
    for (int ii = 0; ii < IT; ++ii)
#pragma unroll
        for (int jtl = 0; jtl < NJT; ++jtl) e[ii][jtl] = 0.f;

    const float4* xlT4 = (const float4*)xlT + (size_t)(b * 32 + h * 8) * N;
    const float*  xrb  = xr + (size_t)(b * N + i0) * OUT_DIM + h * PER_HEAD;

#pragma unroll 1
    for (int ch = 0; ch < NCH; ++ch) {
        // 4 channels/chunk: 2 packed att pairs (uniform -> scalar regs)
        const int c0 = h * PER_HEAD + ch * 4;
        const v2f att0 = mk2(0.4f * att[c0 + 0], 0.4f * att[c0 + 1]);
        const v2f att1 = mk2(0.4f * att[c0 + 2], 0.4f * att[c0 + 3]);
        // hoist the 4 targets' xr chunk (jtl-invariant): 16 VGPR
        float4 xrv[IT];
#pragma unroll
        for (int ii = 0; ii < IT; ++ii)
            xrv[ii] = *(const float4*)(xrb + (size_t)ii * OUT_DIM + ch * 4);
#pragma unroll
        for (int jtl = 0; jtl < NJT; ++jtl) {
            const int jt = wv + jtl * WV;
            const int j  = jt * 64 + lane;
            const float4 xlv = xlT4[ch * N + j];
            const v2f xl0 = mk2(xlv.x, xlv.y);
            const v2f xl1 = mk2(xlv.z, xlv.w);
#pragma unroll
            for (int ii = 0; ii < IT; ++ii) {
                v2f s0 = mk2(xrv[ii].x, xrv[ii].y) + xl0;   // v_pk_add_f32
                v2f s1 = mk2(xrv[ii].z, xrv[ii].w) + xl1;
                s0 = __builtin_elementwise_max(s0, -s0);    // v_pk_max_f32
                s1 = __builtin_elementwise_max(s1, -s1);
                v2f acc = att0 * s0;                        // v_pk_mul_f32
                acc = __builtin_elementwise_fma(att1, s1, acc); // v_pk_fma
                e[ii][jtl] += acc.x + acc.y;
            }
        }
    }

    // ---- finalize scores: 0.6*(axr_i + axl_j) + mask ----
    float axr_i[IT];
#pragma unroll
    for (int ii = 0; ii < IT; ++ii)
        axr_i[ii] = axr[(b * HEADS + h) * N + i0 + ii];
    const float* axlh = axl + (size_t)(b * HEADS + h) * N;
#pragma unroll
    for (int jtl = 0; jtl < NJT; ++jtl) {
        const int jt = wv + jtl * WV;
        const int j  = jt * 64 + lane;
        const float alj = axlh[j];
#pragma unroll
        for (int ii = 0; ii < IT; ++ii) {
            const unsigned long long m =
                maskT[(size_t)(b * N + i0 + ii) * NT + jt];
            const float ev = fmaf(0.6f, axr_i[ii] + alj, e[ii][jtl]);
            e[ii][jtl] = ((m >> lane) & 1ull) ? ev : -1e30f;
        }
    }

    // ---- Phase 2a: per-wave max -> LDS ----
#pragma unroll
    for (int ii = 0; ii < IT; ++ii) {
        float m = fmaxf(fmaxf(e[ii][0], e[ii][1]), fmaxf(e[ii][2], e[ii][3]));
#pragma unroll
        for (int d = 1; d < 64; d <<= 1) m = fmaxf(m, __shfl_xor(m, d));
        if (lane == 0) red[0][ii][wv] = m;
    }
    __syncthreads();

    // ---- Phase 2b: global max, exp, per-wave sum -> LDS ----
#pragma unroll
    for (int ii = 0; ii < IT; ++ii) {
        const float m = fmaxf(red[0][ii][0], red[0][ii][1]);
        float ps = 0.f;
#pragma unroll
        for (int jtl = 0; jtl < NJT; ++jtl) {
            const int jt = wv + jtl * WV;
            const int j  = jt * 64 + lane;
            const float a = __expf(e[ii][jtl] - m);
            a_s[ii][j] = a;
            ps += a;
        }
#pragma unroll
        for (int d = 1; d < 64; d <<= 1) ps += __shfl_xor(ps, d);
        if (lane == 0) red[1][ii][wv] = ps;
    }
    // no barrier: a_s slices are wave-private; red[1] is read only after the
    // phase-3 barrier below.

    // ---- Phase 3: aggregation over own 4 j-tiles; LDS partial reduce ----
    const int c4 = (lane & 7) * 4;
    const int jg = lane >> 3;
    const float* xlb = xl + (size_t)(b * N) * OUT_DIM + h * PER_HEAD + c4;

    v2f accA[IT], accB[IT];
#pragma unroll
    for (int ii = 0; ii < IT; ++ii) {
        accA[ii] = mk2(0.f, 0.f);
        accB[ii] = mk2(0.f, 0.f);
    }
#pragma unroll
    for (int jtl = 0; jtl < NJT; ++jtl) {
        const int jt = wv + jtl * WV;
#pragma unroll
        for (int jo = 0; jo < 8; ++jo) {
            const int jj = jt * 64 + jo * 8 + jg;
            const float4 xv = *(const float4*)(xlb + (size_t)jj * OUT_DIM);
            const v2f x0 = mk2(xv.x, xv.y);
            const v2f x1 = mk2(xv.z, xv.w);
#pragma unroll
            for (int ii = 0; ii < IT; ++ii) {
                const float av = a_s[ii][jj];
                const v2f av2 = mk2(av, av);
                accA[ii] = __builtin_elementwise_fma(av2, x0, accA[ii]);
                accB[ii] = __builtin_elementwise_fma(av2, x1, accB[ii]);
            }
        }
    }
#pragma unroll
    for (int ii = 0; ii < IT; ++ii) {
        float rx = accA[ii].x, ry = accA[ii].y;
        float rz = accB[ii].x, rw = accB[ii].y;
#pragma unroll
        for (int d = 8; d < 64; d <<= 1) {
            rx += __shfl_xor(rx, d);
            ry += __shfl_xor(ry, d);
            rz += __shfl_xor(rz, d);
            rw += __shfl_xor(rw, d);
        }
        if (jg == 0)
            *(float4*)&part[wv][ii][c4] = make_float4(rx, ry, rz, rw);
    }
    __syncthreads();

    // ---- finalize: all 128 threads -> (ii = tid>>5, c = tid&31) ----
    {
        const int ii = tid >> 5;
        const int c  = tid & 31;
        float v = 0.f;
#pragma unroll
        for (int w = 0; w < WV; ++w) v += part[w][ii][c];
        const float ssum = red[1][ii][0] + red[1][ii][1];
        const float s = 1.f / ssum;
        out[(size_t)(b * N + i0 + ii) * OUT_DIM + h * PER_HEAD + c] =
            v * s + bias[h * PER_HEAD + c];
    }
}

extern "C" void kernel_launch(void* const* d_in, const int* in_sizes, int n_in,
                              void* d_out, int out_size, void* d_ws, size_t ws_size,
                              hipStream_t stream) {
    const float* x    = (const float*)d_in[0];
    const int*   adj  = (const int*)d_in[1];
    const float* Wl   = (const float*)d_in[2];
    const float* bl   = (const float*)d_in[3];
    const float* Wr   = (const float*)d_in[4];
    const float* br   = (const float*)d_in[5];
    const float* att  = (const float*)d_in[6];
    const float* bias = (const float*)d_in[7];
    float* out = (float*)d_out;

    char* ws = (char*)d_ws;
    float* xl   = (float*)(ws);                         // 1 MB
    float* xr   = (float*)(ws + (1u << 20));            // 1 MB
    float* xlT  = (float*)(ws + (2u << 20));            // 1 MB
    unsigned long long* maskT =
        (unsigned long long*)(ws + (3u << 20));         // 128 KB
    float* axl  = (float*)(ws + (3u << 20) + (1u << 17));              // 32 KB
    float* axr  = (float*)(ws + (3u << 20) + (1u << 17) + (1u << 15)); // 32 KB

    gat_prep<<<dim3(LIN_BLOCKS + MASK_BLOCKS), dim3(128), 0, stream>>>(
        x, Wl, bl, Wr, br, att, adj, xl, xr, xlT, axl, axr, maskT);
    gat_attn<<<dim3(N / IT, HEADS, B), dim3(128), 0, stream>>>(
        xl, xr, xlT, axl, axr, maskT, att, bias, out);
}